// Round 1
// baseline (293.382 us; speedup 1.0000x reference)
//
#include <hip/hip_runtime.h>
#include <stdint.h>

// ---------------------------------------------------------------------------
// LazyGGUFLinear: y = x @ dequant(scales, codes)^T   (M=N=K=4096)
// R3: replace m97-class 128^2 2-barrier GEMM (~520 TF) with the 8-phase 256^2
//     schedule (T2 swizzle + T3/T4 counted-vmcnt pipeline + T5 setprio + T1
//     XCD rectangle). LDS split by K-half so each phase frees exactly the
//     region the next prefetch overwrites; vmcnt(6) never drains in-loop.
// ---------------------------------------------------------------------------

#define M_DIM 4096
#define N_DIM 4096
#define K_DIM 4096
#define NT    64            // K-tiles of BK=64

typedef __attribute__((ext_vector_type(8))) short bf16x8;   // 8 bf16 = 4 VGPRs
typedef __attribute__((ext_vector_type(4))) float f32x4;    // MFMA C/D

__device__ __forceinline__ unsigned short f32_to_bf16_rne(float f) {
    unsigned u = __float_as_uint(f);
    u += 0x7fffu + ((u >> 16) & 1u);   // round-to-nearest-even
    return (unsigned short)(u >> 16);
}

__device__ __forceinline__ void load_lds16(const void* g, void* l) {
    // async global->LDS, 16 B per lane; LDS dest = wave-uniform base + lane*16
    __builtin_amdgcn_global_load_lds(
        (const __attribute__((address_space(1))) unsigned int*)g,
        (__attribute__((address_space(3))) unsigned int*)l, 16, 0, 0);
}

// ---- fused prologue: blocks [0,8192) dequant W, [8192,16384) convert x -----
__global__ __launch_bounds__(256) void prologue_kernel(
        const int* __restrict__ codes, const float* __restrict__ scales,
        unsigned short* __restrict__ W,
        const float* __restrict__ x, unsigned short* __restrict__ xb) {
    const int bid = blockIdx.x;
    if (bid < 8192) {
        const int tid = bid * 256 + threadIdx.x;          // 2,097,152 threads
        const int o   = tid >> 9;
        const int blk = (tid & 511) >> 2;
        const float s = scales[o * 128 + blk];
        const int4 c0 = ((const int4*)codes)[(size_t)tid * 2];
        const int4 c1 = ((const int4*)codes)[(size_t)tid * 2 + 1];
        union { unsigned short u[8]; uint4 v; } p;
        p.u[0] = f32_to_bf16_rne(s * (float)(c0.x - 128));
        p.u[1] = f32_to_bf16_rne(s * (float)(c0.y - 128));
        p.u[2] = f32_to_bf16_rne(s * (float)(c0.z - 128));
        p.u[3] = f32_to_bf16_rne(s * (float)(c0.w - 128));
        p.u[4] = f32_to_bf16_rne(s * (float)(c1.x - 128));
        p.u[5] = f32_to_bf16_rne(s * (float)(c1.y - 128));
        p.u[6] = f32_to_bf16_rne(s * (float)(c1.z - 128));
        p.u[7] = f32_to_bf16_rne(s * (float)(c1.w - 128));
        ((uint4*)W)[tid] = p.v;
    } else {
        const int tid = (bid - 8192) * 256 + threadIdx.x; // one per 8 floats
        const float4 f0 = ((const float4*)x)[(size_t)tid * 2];
        const float4 f1 = ((const float4*)x)[(size_t)tid * 2 + 1];
        union { unsigned short u[8]; uint4 v; } p;
        p.u[0] = f32_to_bf16_rne(f0.x); p.u[1] = f32_to_bf16_rne(f0.y);
        p.u[2] = f32_to_bf16_rne(f0.z); p.u[3] = f32_to_bf16_rne(f0.w);
        p.u[4] = f32_to_bf16_rne(f1.x); p.u[5] = f32_to_bf16_rne(f1.y);
        p.u[6] = f32_to_bf16_rne(f1.z); p.u[7] = f32_to_bf16_rne(f1.w);
        ((uint4*)xb)[tid] = p.v;
    }
}

// ---- sync / pipeline primitives -------------------------------------------
#define BAR()   asm volatile("s_barrier" ::: "memory")
#define LGKM0() asm volatile("s_waitcnt lgkmcnt(0)" ::: "memory")
#define VMC(N)  asm volatile("s_waitcnt vmcnt(" #N ")" ::: "memory")

// ---- 8-phase 256x256 bf16 GEMM, both operands K-major ----------------------
// LDS: per operand 2 dbuf x 2 khalf regions of [256 rows][32 k] bf16 (16 KB).
// Swizzle: region chunk' = chunk ^ ((row>>1)&3)  (chunk = 16B unit, 4/row).
//   Staging pre-swizzles the GLOBAL source k-offset (LDS dest stays linear,
//   required by global_load_lds); ds_read applies the same XOR. Any 8
//   consecutive lanes of ds_read_b128 then hit all 32 banks.
// Issue stream: prologue stages halves 0..6; phase p of tile t stages half
//   7+4t+(p-1); order per tile = [A-k0, B-k0, A-k1, B-k1]. vmcnt(6) at each
//   P4 == "3 halves in flight", completing exactly through tile t+1's B-k1.
__global__ __launch_bounds__(512, 2) void gemm_8phase(
        const unsigned short* __restrict__ A,   // [M,K] bf16 (x)
        const unsigned short* __restrict__ B,   // [N,K] bf16 (W)
        float* __restrict__ C) {                // [M,N] fp32
    __shared__ unsigned short sA[2][2][256 * 32];   // 64 KB
    __shared__ unsigned short sB[2][2][256 * 32];   // 64 KB

    const int tid  = threadIdx.x;
    const int wave = tid >> 6;
    const int lane = tid & 63;

    // XCD rectangle swizzle: 256 blocks co-resident, xcd = bid%8 owns an
    // 8(m) x 4(n) rectangle of the 16x16 tile grid.
    const int bid  = blockIdx.x;
    const int xcd  = bid & 7;
    const int slot = bid >> 3;                        // 0..31
    const int m0 = ((xcd >> 2) * 8 + (slot >> 2)) * 256;
    const int n0 = ((xcd & 3) * 4 + (slot & 3)) * 256;

    // staging: wave w covers region rows [w*32, w*32+32), 2 calls of 16 rows.
    // lane -> row w*32 + c*16 + (lane>>2), 16B chunk (lane&3)^((lane>>3)&3).
    const int srow   = lane >> 2;
    const int schunk = (lane & 3) ^ ((lane >> 3) & 3);   // pre-swizzled source
    const unsigned short* Ag = A + (size_t)(m0 + wave * 32 + srow) * K_DIM + schunk * 8;
    const unsigned short* Bg = B + (size_t)(n0 + wave * 32 + srow) * K_DIM + schunk * 8;
    const int ldsW = wave * 1024;                        // element offset, call 0

    // fragments: wave (wm,wn) owns C rows [wm*128,+128) x cols [wn*64,+64)
    const int frow = lane & 15;
    const int quad = lane >> 4;
    const int wm = wave >> 2;
    const int wn = wave & 3;
    const int cswz = (quad ^ ((frow >> 1) & 3)) * 8;     // swizzled k-chunk
    const int aOff = (wm * 128 + frow) * 32 + cswz;
    const int bOff = (wn * 64 + frow) * 32 + cswz;

    f32x4 acc[8][4] = {};
    bf16x8 a[8], b0, b1, b2, b3;

#define STG_A(BUF, KH, KT) do { \
        const unsigned short* s_ = Ag + (size_t)(KT) * 64 + (KH) * 32; \
        load_lds16(s_,                       &sA[BUF][KH][ldsW]); \
        load_lds16(s_ + (size_t)16 * K_DIM,  &sA[BUF][KH][ldsW + 512]); \
    } while (0)
#define STG_B(BUF, KH, KT) do { \
        const unsigned short* s_ = Bg + (size_t)(KT) * 64 + (KH) * 32; \
        load_lds16(s_,                       &sB[BUF][KH][ldsW]); \
        load_lds16(s_ + (size_t)16 * K_DIM,  &sB[BUF][KH][ldsW + 512]); \
    } while (0)
#define RD_A(BUF, KH) do { _Pragma("unroll") \
        for (int mt_ = 0; mt_ < 8; ++mt_) \
            a[mt_] = *(const bf16x8*)&sA[BUF][KH][aOff + mt_ * 512]; \
    } while (0)
#define RD_B2(BUF, KH, NB, R0, R1) do { \
        R0 = *(const bf16x8*)&sB[BUF][KH][bOff + (NB) * 512]; \
        R1 = *(const bf16x8*)&sB[BUF][KH][bOff + (NB + 1) * 512]; \
    } while (0)
#define MM2(NC, R0, R1) do { _Pragma("unroll") \
        for (int mt_ = 0; mt_ < 8; ++mt_) { \
            acc[mt_][NC]     = __builtin_amdgcn_mfma_f32_16x16x32_bf16(a[mt_], R0, acc[mt_][NC],     0, 0, 0); \
            acc[mt_][NC + 1] = __builtin_amdgcn_mfma_f32_16x16x32_bf16(a[mt_], R1, acc[mt_][NC + 1], 0, 0, 0); \
        } } while (0)

// One K-tile = 4 phases. Each phase: {ds_read regs | issue 1 half-tile} ->
// barrier -> lgkm(0) -> prio1 -> 16 MFMA -> prio0 -> [vmcnt @P4] -> barrier.
// Region freed per phase == region the staged half overwrites (A-k0 after P1,
// B-k0 after P2, A-k1 after P3, B-k1 of OBUF before P1).
#define KTILE(BUF, OBUF, T, I1, I2, I3, I4, VMF) do { \
        /* P1: k0, n0-1 */ \
        RD_A(BUF, 0); RD_B2(BUF, 0, 0, b0, b1); \
        if (I1) { STG_B(OBUF, 1, (T) + 1); } \
        BAR(); LGKM0(); __builtin_amdgcn_s_setprio(1); \
        MM2(0, b0, b1); \
        __builtin_amdgcn_s_setprio(0); BAR(); \
        /* P2: k0, n2-3 */ \
        RD_B2(BUF, 0, 2, b2, b3); \
        if (I2) { STG_A(BUF, 0, (T) + 2); } \
        BAR(); LGKM0(); __builtin_amdgcn_s_setprio(1); \
        MM2(2, b2, b3); \
        __builtin_amdgcn_s_setprio(0); BAR(); \
        /* P3: k1, n0-1 */ \
        RD_A(BUF, 1); RD_B2(BUF, 1, 0, b0, b1); \
        if (I3) { STG_B(BUF, 0, (T) + 2); } \
        BAR(); LGKM0(); __builtin_amdgcn_s_setprio(1); \
        MM2(0, b0, b1); \
        __builtin_amdgcn_s_setprio(0); BAR(); \
        /* P4: k1, n2-3 */ \
        RD_B2(BUF, 1, 2, b2, b3); \
        if (I4) { STG_A(BUF, 1, (T) + 2); } \
        BAR(); LGKM0(); __builtin_amdgcn_s_setprio(1); \
        MM2(2, b2, b3); \
        __builtin_amdgcn_s_setprio(0); \
        VMF; BAR(); \
    } while (0)

    // pipeline prologue: tile 0 fully + tile 1 first 3 halves (14 loads);
    // vmcnt(6) -> tile 0 resident, 3 halves in flight.
    STG_A(0, 0, 0); STG_B(0, 0, 0); STG_A(0, 1, 0); STG_B(0, 1, 0);
    STG_A(1, 0, 1); STG_B(1, 0, 1); STG_A(1, 1, 1);
    VMC(6); BAR();

#pragma unroll 1
    for (int t2 = 0; t2 < 31; ++t2) {               // tiles 0..61
        const int t = t2 * 2;
        KTILE(0, 1, t,     1, 1, 1, 1, VMC(6));
        KTILE(1, 0, t + 1, 1, 1, 1, 1, VMC(6));
    }
    KTILE(0, 1, 62, 1, 0, 0, 0, VMC(0));            // last issue: B-k1 of 63
    KTILE(1, 0, 63, 0, 0, 0, 0, (void)0);

    // epilogue: C/D layout col = lane&15, row = quad*4 + r  [m89/m91]
    const size_t crow0 = (size_t)(m0 + wm * 128 + quad * 4);
    const int    ccol  = n0 + wn * 64 + frow;
#pragma unroll
    for (int mt = 0; mt < 8; ++mt)
#pragma unroll
        for (int nt = 0; nt < 4; ++nt)
#pragma unroll
            for (int r = 0; r < 4; ++r)
                C[(crow0 + mt * 16 + r) * N_DIM + ccol + nt * 16] = acc[mt][nt][r];

#undef STG_A
#undef STG_B
#undef RD_A
#undef RD_B2
#undef MM2
#undef KTILE
}

extern "C" void kernel_launch(void* const* d_in, const int* in_sizes, int n_in,
                              void* d_out, int out_size, void* d_ws, size_t ws_size,
                              hipStream_t stream) {
    const float* x      = (const float*)d_in[0];   // 2*2048*4096 fp32
    const float* scales = (const float*)d_in[1];   // 4096*128 fp32
    const int*   codes  = (const int*)d_in[2];     // 4096*128*32 int32
    float* y = (float*)d_out;                      // 4096*4096 fp32

    unsigned short* Wb = (unsigned short*)d_ws;                       // 32 MB
    unsigned short* xb = (unsigned short*)((char*)d_ws + (size_t)N_DIM * K_DIM * 2); // 32 MB

    prologue_kernel<<<16384, 256, 0, stream>>>(codes, scales, Wb, x, xb);

    gemm_8phase<<<256, 512, 0, stream>>>(xb, Wb, y);
}

// Round 2
// 290.196 us; speedup vs baseline: 1.0110x; 1.0110x over previous
//
#include <hip/hip_runtime.h>
#include <stdint.h>

// ---------------------------------------------------------------------------
// LazyGGUFLinear: y = x @ dequant(scales, codes)^T   (M=N=K=4096)
// R4: rebalance 8-phase GEMM reads from (10,2,10,2) to the template's
//     (8,4,8,4): phase = half-M x all-N quadrant, B held in regs across the
//     phase pair, A re-read per phase. Port burst (960cy) no longer
//     serializes against the 516cy MFMA cluster. Prologue: fully-contiguous
//     1-int4-per-thread loads (was stride-32B pairs).
// ---------------------------------------------------------------------------

#define M_DIM 4096
#define N_DIM 4096
#define K_DIM 4096

typedef __attribute__((ext_vector_type(8))) short bf16x8;   // 8 bf16 = 4 VGPRs
typedef __attribute__((ext_vector_type(4))) float f32x4;    // MFMA C/D

__device__ __forceinline__ unsigned short f32_to_bf16_rne(float f) {
    unsigned u = __float_as_uint(f);
    u += 0x7fffu + ((u >> 16) & 1u);   // round-to-nearest-even
    return (unsigned short)(u >> 16);
}

__device__ __forceinline__ void load_lds16(const void* g, void* l) {
    // async global->LDS, 16 B per lane; LDS dest = wave-uniform base + lane*16
    __builtin_amdgcn_global_load_lds(
        (const __attribute__((address_space(1))) unsigned int*)g,
        (__attribute__((address_space(3))) unsigned int*)l, 16, 0, 0);
}

// ---- fused prologue: blocks [0,16384) dequant W, [16384,32768) convert x ---
// Fully coalesced: each thread = one 16B load, one 8B store.
__global__ __launch_bounds__(256) void prologue_kernel(
        const int* __restrict__ codes, const float* __restrict__ scales,
        unsigned short* __restrict__ W,
        const float* __restrict__ x, unsigned short* __restrict__ xb) {
    const int bid = blockIdx.x;
    if (bid < 16384) {
        // one thread per int4 = 4 codes (weight idx = tid*4)
        const int tid = bid * 256 + threadIdx.x;      // 0..4,194,303
        const float s = scales[tid >> 3];             // 8 threads share a scale
        const int4 c  = ((const int4*)codes)[tid];
        union { unsigned short u[4]; uint2 v; } p;
        p.u[0] = f32_to_bf16_rne(s * (float)(c.x - 128));
        p.u[1] = f32_to_bf16_rne(s * (float)(c.y - 128));
        p.u[2] = f32_to_bf16_rne(s * (float)(c.z - 128));
        p.u[3] = f32_to_bf16_rne(s * (float)(c.w - 128));
        ((uint2*)W)[tid] = p.v;
    } else {
        // one thread per float4
        const int tid = (bid - 16384) * 256 + threadIdx.x;
        const float4 f = ((const float4*)x)[tid];
        union { unsigned short u[4]; uint2 v; } p;
        p.u[0] = f32_to_bf16_rne(f.x); p.u[1] = f32_to_bf16_rne(f.y);
        p.u[2] = f32_to_bf16_rne(f.z); p.u[3] = f32_to_bf16_rne(f.w);
        ((uint2*)xb)[tid] = p.v;
    }
}

// ---- sync / pipeline primitives -------------------------------------------
#define BAR()   asm volatile("s_barrier" ::: "memory")
#define LGKM0() asm volatile("s_waitcnt lgkmcnt(0)" ::: "memory")
#define VMC(N)  asm volatile("s_waitcnt vmcnt(" #N ")" ::: "memory")

// ---- 8-phase 256x256 bf16 GEMM, both operands K-major ----------------------
// LDS: per operand 2 dbuf x 2 khalf regions of [256 rows][32 k] bf16 (16 KB).
// Swizzle: chunk' = chunk ^ ((row>>1)&3); staging pre-swizzles the GLOBAL
//   source k-offset (LDS dest linear, required by global_load_lds); ds_read
//   applies the same XOR -> any 8 lanes of ds_read_b128 cover all 32 banks.
// Phases per K-tile (reads 8,4,8,4):
//   P1: rd a[mt0-3]+b[nc0-3] kh0 | stage A1(T+1)->OBUF | MFMA mt0-3 x nc0-3
//   P2: rd a[mt4-7]          kh0 | stage B0(T+2)->BUF  | MFMA mt4-7 (b reuse)
//   P3: rd a[mt0-3]+b[nc0-3] kh1 | stage A0(T+2)->BUF  | MFMA mt0-3
//   P4: rd a[mt4-7]          kh1 | stage B1(T+2)->BUF  | MFMA mt4-7, vmcnt(6)
// Staged region is always the one fully consumed before the previous barrier.
// vmcnt(6) at P4: outstanding can be 14 (6 carried + 8 this tile); completing
// the 8 oldest == all four halves of tile T+1 resident; 6 (T+2) stay in flight.
__global__ __launch_bounds__(512, 2) void gemm_8phase(
        const unsigned short* __restrict__ A,   // [M,K] bf16 (x)
        const unsigned short* __restrict__ B,   // [N,K] bf16 (W)
        float* __restrict__ C) {                // [M,N] fp32
    __shared__ unsigned short sA[2][2][256 * 32];   // 64 KB
    __shared__ unsigned short sB[2][2][256 * 32];   // 64 KB

    const int tid  = threadIdx.x;
    const int wave = tid >> 6;
    const int lane = tid & 63;

    // XCD rectangle swizzle: xcd = bid%8 owns an 8(m) x 4(n) tile rectangle.
    const int bid  = blockIdx.x;
    const int xcd  = bid & 7;
    const int slot = bid >> 3;                        // 0..31
    const int m0 = ((xcd >> 2) * 8 + (slot >> 2)) * 256;
    const int n0 = ((xcd & 3) * 4 + (slot & 3)) * 256;

    // staging: wave w covers region rows [w*32, w*32+32), 2 calls of 16 rows.
    const int srow   = lane >> 2;
    const int schunk = (lane & 3) ^ ((lane >> 3) & 3);   // pre-swizzled source
    const unsigned short* Ag = A + (size_t)(m0 + wave * 32 + srow) * K_DIM + schunk * 8;
    const unsigned short* Bg = B + (size_t)(n0 + wave * 32 + srow) * K_DIM + schunk * 8;
    const int ldsW = wave * 1024;                        // element offset, call 0

    // fragments: wave (wm,wn) owns C rows [wm*128,+128) x cols [wn*64,+64)
    const int frow = lane & 15;
    const int quad = lane >> 4;
    const int wm = wave >> 2;
    const int wn = wave & 3;
    const int cswz = (quad ^ ((frow >> 1) & 3)) * 8;     // swizzled k-chunk
    const int aOff = (wm * 128 + frow) * 32 + cswz;
    const int bOff = (wn * 64 + frow) * 32 + cswz;

    f32x4 acc[8][4] = {};
    bf16x8 a[4], b[4];

#define STG_A(BUF, KH, KT) do { \
        const unsigned short* s_ = Ag + (size_t)(KT) * 64 + (KH) * 32; \
        load_lds16(s_,                       &sA[BUF][KH][ldsW]); \
        load_lds16(s_ + (size_t)16 * K_DIM,  &sA[BUF][KH][ldsW + 512]); \
    } while (0)
#define STG_B(BUF, KH, KT) do { \
        const unsigned short* s_ = Bg + (size_t)(KT) * 64 + (KH) * 32; \
        load_lds16(s_,                       &sB[BUF][KH][ldsW]); \
        load_lds16(s_ + (size_t)16 * K_DIM,  &sB[BUF][KH][ldsW + 512]); \
    } while (0)
#define RD_A4(BUF, KH, MH) do { _Pragma("unroll") \
        for (int i_ = 0; i_ < 4; ++i_) \
            a[i_] = *(const bf16x8*)&sA[BUF][KH][aOff + ((MH) * 4 + i_) * 512]; \
    } while (0)
#define RD_B4(BUF, KH) do { _Pragma("unroll") \
        for (int i_ = 0; i_ < 4; ++i_) \
            b[i_] = *(const bf16x8*)&sB[BUF][KH][bOff + i_ * 512]; \
    } while (0)
#define MM16(MH) do { _Pragma("unroll") \
        for (int i_ = 0; i_ < 4; ++i_) { _Pragma("unroll") \
            for (int n_ = 0; n_ < 4; ++n_) \
                acc[(MH) * 4 + i_][n_] = __builtin_amdgcn_mfma_f32_16x16x32_bf16( \
                    a[i_], b[n_], acc[(MH) * 4 + i_][n_], 0, 0, 0); \
        } } while (0)

#define KTILE(BUF, OBUF, T, I1, I2, I3, I4, VMF) do { \
        /* P1: kh0, mt0-3 x nc0-3 */ \
        RD_A4(BUF, 0, 0); RD_B4(BUF, 0); \
        if (I1) { STG_A(OBUF, 1, (T) + 1); } \
        BAR(); LGKM0(); __builtin_amdgcn_s_setprio(1); \
        MM16(0); \
        __builtin_amdgcn_s_setprio(0); BAR(); \
        /* P2: kh0, mt4-7 (b reused) */ \
        RD_A4(BUF, 0, 1); \
        if (I2) { STG_B(BUF, 0, (T) + 2); } \
        BAR(); LGKM0(); __builtin_amdgcn_s_setprio(1); \
        MM16(1); \
        __builtin_amdgcn_s_setprio(0); BAR(); \
        /* P3: kh1, mt0-3 */ \
        RD_A4(BUF, 1, 0); RD_B4(BUF, 1); \
        if (I3) { STG_A(BUF, 0, (T) + 2); } \
        BAR(); LGKM0(); __builtin_amdgcn_s_setprio(1); \
        MM16(0); \
        __builtin_amdgcn_s_setprio(0); BAR(); \
        /* P4: kh1, mt4-7 */ \
        RD_A4(BUF, 1, 1); \
        if (I4) { STG_B(BUF, 1, (T) + 2); } \
        BAR(); LGKM0(); __builtin_amdgcn_s_setprio(1); \
        MM16(1); \
        __builtin_amdgcn_s_setprio(0); \
        VMF; BAR(); \
    } while (0)

    // pipeline prologue: tile 0 all 4 halves + tile 1's B0,A0,B1 (14 loads);
    // vmcnt(6) -> tile 0 resident, 3 halves (6 loads) in flight.
    STG_A(0, 0, 0); STG_B(0, 0, 0); STG_A(0, 1, 0); STG_B(0, 1, 0);
    STG_B(1, 0, 1); STG_A(1, 0, 1); STG_B(1, 1, 1);
    VMC(6); BAR();

#pragma unroll 1
    for (int t2 = 0; t2 < 31; ++t2) {               // tiles 0..61
        const int t = t2 * 2;
        KTILE(0, 1, t,     1, 1, 1, 1, VMC(6));
        KTILE(1, 0, t + 1, 1, 1, 1, 1, VMC(6));
    }
    KTILE(0, 1, 62, 1, 0, 0, 0, VMC(0));            // last issue: A1(63)
    KTILE(1, 0, 63, 0, 0, 0, 0, (void)0);

    // epilogue: C/D layout col = lane&15, row = quad*4 + r  [m89/m91]
    const size_t crow0 = (size_t)(m0 + wm * 128 + quad * 4);
    const int    ccol  = n0 + wn * 64 + frow;
#pragma unroll
    for (int mt = 0; mt < 8; ++mt)
#pragma unroll
        for (int nt = 0; nt < 4; ++nt)
#pragma unroll
            for (int r = 0; r < 4; ++r)
                C[(crow0 + mt * 16 + r) * N_DIM + ccol + nt * 16] = acc[mt][nt][r];

#undef STG_A
#undef STG_B
#undef RD_A4
#undef RD_B4
#undef MM16
#undef KTILE
}

extern "C" void kernel_launch(void* const* d_in, const int* in_sizes, int n_in,
                              void* d_out, int out_size, void* d_ws, size_t ws_size,
                              hipStream_t stream) {
    const float* x      = (const float*)d_in[0];   // 2*2048*4096 fp32
    const float* scales = (const float*)d_in[1];   // 4096*128 fp32
    const int*   codes  = (const int*)d_in[2];     // 4096*128*32 int32
    float* y = (float*)d_out;                      // 4096*4096 fp32

    unsigned short* Wb = (unsigned short*)d_ws;                       // 32 MB
    unsigned short* xb = (unsigned short*)((char*)d_ws + (size_t)N_DIM * K_DIM * 2); // 32 MB

    prologue_kernel<<<32768, 256, 0, stream>>>(codes, scales, Wb, x, xb);

    gemm_8phase<<<256, 512, 0, stream>>>(xb, Wb, y);
}

// Round 4
// 287.975 us; speedup vs baseline: 1.0188x; 1.0077x over previous
//
#include <hip/hip_runtime.h>
#include <stdint.h>

// ---------------------------------------------------------------------------
// LazyGGUFLinear: y = x @ dequant(scales, codes)^T   (M=N=K=4096)
// R6 = R5 resubmit (container infra flake, no signal). Read-ahead register
//     pipeline: phase p reads operand group G_{p+1} into the alternate reg
//     set and MFMAs G_p (whose ds_reads drained during phase p-1). Compiler
//     emits counted lgkm waits. vmcnt ledger: VMC(8)@ph2, VMC(6)@ph3
//     (re-audited: kh0(T+1) resident for ph3's G0' read-ahead; kh1(T+1) by
//     T+1.ph1; tail VMC(4)/VMC(0) covers tile 63).
// ---------------------------------------------------------------------------

#define M_DIM 4096
#define N_DIM 4096
#define K_DIM 4096

typedef __attribute__((ext_vector_type(8))) short bf16x8;   // 8 bf16 = 4 VGPRs
typedef __attribute__((ext_vector_type(4))) float f32x4;    // MFMA C/D

__device__ __forceinline__ unsigned short f32_to_bf16_rne(float f) {
    unsigned u = __float_as_uint(f);
    u += 0x7fffu + ((u >> 16) & 1u);   // round-to-nearest-even
    return (unsigned short)(u >> 16);
}

__device__ __forceinline__ void load_lds16(const void* g, void* l) {
    // async global->LDS, 16 B per lane; LDS dest = wave-uniform base + lane*16
    __builtin_amdgcn_global_load_lds(
        (const __attribute__((address_space(1))) unsigned int*)g,
        (__attribute__((address_space(3))) unsigned int*)l, 16, 0, 0);
}

// ---- fused prologue: blocks [0,16384) dequant W, [16384,32768) convert x ---
__global__ __launch_bounds__(256) void prologue_kernel(
        const int* __restrict__ codes, const float* __restrict__ scales,
        unsigned short* __restrict__ W,
        const float* __restrict__ x, unsigned short* __restrict__ xb) {
    const int bid = blockIdx.x;
    if (bid < 16384) {
        const int tid = bid * 256 + threadIdx.x;      // one thread per int4
        const float s = scales[tid >> 3];             // 8 threads share a scale
        const int4 c  = ((const int4*)codes)[tid];
        union { unsigned short u[4]; uint2 v; } p;
        p.u[0] = f32_to_bf16_rne(s * (float)(c.x - 128));
        p.u[1] = f32_to_bf16_rne(s * (float)(c.y - 128));
        p.u[2] = f32_to_bf16_rne(s * (float)(c.z - 128));
        p.u[3] = f32_to_bf16_rne(s * (float)(c.w - 128));
        ((uint2*)W)[tid] = p.v;
    } else {
        const int tid = (bid - 16384) * 256 + threadIdx.x;  // one per float4
        const float4 f = ((const float4*)x)[tid];
        union { unsigned short u[4]; uint2 v; } p;
        p.u[0] = f32_to_bf16_rne(f.x); p.u[1] = f32_to_bf16_rne(f.y);
        p.u[2] = f32_to_bf16_rne(f.z); p.u[3] = f32_to_bf16_rne(f.w);
        ((uint2*)xb)[tid] = p.v;
    }
}

// ---- sync / pipeline primitives -------------------------------------------
#define BAR()   asm volatile("s_barrier" ::: "memory")
#define VMC(N)  asm volatile("s_waitcnt vmcnt(" #N ")" ::: "memory")
#define SB0()   __builtin_amdgcn_sched_barrier(0)

// ---- 8-phase 256x256 bf16 GEMM, both operands K-major, read-ahead regs ----
// LDS: per operand 2 dbuf x 2 khalf regions of [256 rows][32 k] bf16 (16 KB).
// Swizzle: chunk' = chunk ^ ((row>>1)&3); staging pre-swizzles the GLOBAL
//   source k-offset (LDS dest linear); ds_read applies the same XOR.
// Operand groups per K-tile: G0={kh0:a(mh0),b0} G1={kh0:a(mh1)} (b0 reused)
//   G2={kh1:a(mh0),b1} G3={kh1:a(mh1)}. Phase p: read G_{p+1} | stage | BAR |
//   MFMA G_p | BAR. a alternates aX(even G)/aY(odd G); b by k-half.
// In-flight ledger (2 loads per STG): tile-start carry = {Bkh0,Akh0,Bkh1}(T+1)
//   =6. ph0 +Akh1(T+1), ph1 +Bkh0(T+2), ph2 +Akh0(T+2): VMC(8) ensures
//   kh0(T+1) resident for ph3's G0' reads. ph3 +Bkh1(T+2): VMC(6) ensures
//   kh1(T+1) resident for T+1.ph1. Tail: VMC(4)/VMC(0) at tile 62.
__global__ __launch_bounds__(512, 2) void gemm_8phase(
        const unsigned short* __restrict__ A,   // [M,K] bf16 (x)
        const unsigned short* __restrict__ B,   // [N,K] bf16 (W)
        float* __restrict__ C) {                // [M,N] fp32
    __shared__ unsigned short sA[2][2][256 * 32];   // 64 KB
    __shared__ unsigned short sB[2][2][256 * 32];   // 64 KB

    const int tid  = threadIdx.x;
    const int wave = tid >> 6;
    const int lane = tid & 63;

    // XCD rectangle swizzle: xcd = bid%8 owns an 8(m) x 4(n) tile rectangle.
    const int bid  = blockIdx.x;
    const int xcd  = bid & 7;
    const int slot = bid >> 3;                        // 0..31
    const int m0 = ((xcd >> 2) * 8 + (slot >> 2)) * 256;
    const int n0 = ((xcd & 3) * 4 + (slot & 3)) * 256;

    // staging: wave w covers region rows [w*32, w*32+32), 2 calls of 16 rows.
    const int srow   = lane >> 2;
    const int schunk = (lane & 3) ^ ((lane >> 3) & 3);   // pre-swizzled source
    const unsigned short* Ag = A + (size_t)(m0 + wave * 32 + srow) * K_DIM + schunk * 8;
    const unsigned short* Bg = B + (size_t)(n0 + wave * 32 + srow) * K_DIM + schunk * 8;
    const int ldsW = wave * 1024;                        // element offset, call 0

    // fragments: wave (wm,wn) owns C rows [wm*128,+128) x cols [wn*64,+64)
    const int frow = lane & 15;
    const int quad = lane >> 4;
    const int wm = wave >> 2;
    const int wn = wave & 3;
    const int cswz = (quad ^ ((frow >> 1) & 3)) * 8;     // swizzled k-chunk
    const int aOff = (wm * 128 + frow) * 32 + cswz;
    const int bOff = (wn * 64 + frow) * 32 + cswz;

    f32x4 acc[8][4] = {};
    bf16x8 aX[4], aY[4], b0r[4], b1r[4];

#define STG_A(BUF, KH, KT) do { \
        const unsigned short* s_ = Ag + (size_t)(KT) * 64 + (KH) * 32; \
        load_lds16(s_,                       &sA[BUF][KH][ldsW]); \
        load_lds16(s_ + (size_t)16 * K_DIM,  &sA[BUF][KH][ldsW + 512]); \
    } while (0)
#define STG_B(BUF, KH, KT) do { \
        const unsigned short* s_ = Bg + (size_t)(KT) * 64 + (KH) * 32; \
        load_lds16(s_,                       &sB[BUF][KH][ldsW]); \
        load_lds16(s_ + (size_t)16 * K_DIM,  &sB[BUF][KH][ldsW + 512]); \
    } while (0)
#define RD_A4(DST, BUF, KH, MH) do { _Pragma("unroll") \
        for (int i_ = 0; i_ < 4; ++i_) \
            DST[i_] = *(const bf16x8*)&sA[BUF][KH][aOff + ((MH) * 4 + i_) * 512]; \
    } while (0)
#define RD_B4(DST, BUF, KH) do { _Pragma("unroll") \
        for (int i_ = 0; i_ < 4; ++i_) \
            DST[i_] = *(const bf16x8*)&sB[BUF][KH][bOff + i_ * 512]; \
    } while (0)
#define MM16(AR, BR, MH) do { _Pragma("unroll") \
        for (int i_ = 0; i_ < 4; ++i_) { _Pragma("unroll") \
            for (int n_ = 0; n_ < 4; ++n_) \
                acc[(MH) * 4 + i_][n_] = __builtin_amdgcn_mfma_f32_16x16x32_bf16( \
                    AR[i_], BR[n_], acc[(MH) * 4 + i_][n_], 0, 0, 0); \
        } } while (0)

#define KTILE(BUF, OBUF, T, I0, I1, I2, I3, VM2, VM3, R3) do { \
        /* ph0: rd G1 | MFMA G0 (aX,b0 -> acc mh0) */ \
        RD_A4(aY, BUF, 0, 1); \
        if (I0) { STG_A(OBUF, 1, (T) + 1); } \
        BAR(); SB0(); \
        __builtin_amdgcn_s_setprio(1); MM16(aX, b0r, 0); __builtin_amdgcn_s_setprio(0); \
        BAR(); \
        /* ph1: rd G2 | MFMA G1 (aY,b0 -> acc mh1) */ \
        RD_A4(aX, BUF, 1, 0); RD_B4(b1r, BUF, 1); \
        if (I1) { STG_B(BUF, 0, (T) + 2); } \
        BAR(); SB0(); \
        __builtin_amdgcn_s_setprio(1); MM16(aY, b0r, 1); __builtin_amdgcn_s_setprio(0); \
        BAR(); \
        /* ph2: rd G3 | MFMA G2 (aX,b1 -> acc mh0) */ \
        RD_A4(aY, BUF, 1, 1); \
        if (I2) { STG_A(BUF, 0, (T) + 2); } \
        BAR(); SB0(); \
        __builtin_amdgcn_s_setprio(1); MM16(aX, b1r, 0); __builtin_amdgcn_s_setprio(0); \
        VM2; BAR(); \
        /* ph3: rd G0' (next tile) | MFMA G3 (aY,b1 -> acc mh1) */ \
        if (R3) { RD_A4(aX, OBUF, 0, 0); RD_B4(b0r, OBUF, 0); } \
        if (I3) { STG_B(BUF, 1, (T) + 2); } \
        BAR(); SB0(); \
        __builtin_amdgcn_s_setprio(1); MM16(aY, b1r, 1); __builtin_amdgcn_s_setprio(0); \
        VM3; BAR(); \
    } while (0)

    // pipeline prologue: tile 0 all 4 halves + tile 1's {Bkh0,Akh0,Bkh1}
    // (14 loads); vmcnt(6) -> tile 0 resident, 3 halves in flight.
    STG_A(0, 0, 0); STG_B(0, 0, 0); STG_A(0, 1, 0); STG_B(0, 1, 0);
    STG_B(1, 0, 1); STG_A(1, 0, 1); STG_B(1, 1, 1);
    VMC(6); BAR();
    // initial register stage: G0 of tile 0
    RD_A4(aX, 0, 0, 0); RD_B4(b0r, 0, 0);

#pragma unroll 1
    for (int t2 = 0; t2 < 31; ++t2) {               // tiles 0..61
        const int t = t2 * 2;
        KTILE(0, 1, t,     1, 1, 1, 1, VMC(8), VMC(6), 1);
        KTILE(1, 0, t + 1, 1, 1, 1, 1, VMC(8), VMC(6), 1);
    }
    KTILE(0, 1, 62, 1, 0, 0, 0, VMC(4), VMC(0), 1); // last issue: Akh1(63)
    KTILE(1, 0, 63, 0, 0, 0, 0, (void)0, (void)0, 0);

    // epilogue: C/D layout col = lane&15, row = quad*4 + r  [m89/m91]
    const size_t crow0 = (size_t)(m0 + wm * 128 + quad * 4);
    const int    ccol  = n0 + wn * 64 + frow;
#pragma unroll
    for (int mt = 0; mt < 8; ++mt)
#pragma unroll
        for (int nt = 0; nt < 4; ++nt)
#pragma unroll
            for (int r = 0; r < 4; ++r)
                C[(crow0 + mt * 16 + r) * N_DIM + ccol + nt * 16] = acc[mt][nt][r];

#undef STG_A
#undef STG_B
#undef RD_A4
#undef RD_B4
#undef MM16
#undef KTILE
}

extern "C" void kernel_launch(void* const* d_in, const int* in_sizes, int n_in,
                              void* d_out, int out_size, void* d_ws, size_t ws_size,
                              hipStream_t stream) {
    const float* x      = (const float*)d_in[0];   // 2*2048*4096 fp32
    const float* scales = (const float*)d_in[1];   // 4096*128 fp32
    const int*   codes  = (const int*)d_in[2];     // 4096*128*32 int32
    float* y = (float*)d_out;                      // 4096*4096 fp32

    unsigned short* Wb = (unsigned short*)d_ws;                       // 32 MB
    unsigned short* xb = (unsigned short*)((char*)d_ws + (size_t)N_DIM * K_DIM * 2); // 32 MB

    prologue_kernel<<<32768, 256, 0, stream>>>(codes, scales, Wb, x, xb);

    gemm_8phase<<<256, 512, 0, stream>>>(xb, Wb, y);
}

// Round 5
// 286.613 us; speedup vs baseline: 1.0236x; 1.0048x over previous
//
#include <hip/hip_runtime.h>
#include <stdint.h>

// ---------------------------------------------------------------------------
// LazyGGUFLinear: y = x @ dequant(scales, codes)^T   (M=N=K=4096)
// R7: fix the self-inflicted barrier drain. R4/R5 used
//     asm volatile("s_barrier":::"memory"), which the backend treats as a
//     memory access -> it inserted s_waitcnt vmcnt(0) lgkmcnt(0) before EVERY
//     barrier (8/K-tile), nullifying the counted-vmcnt pipeline (MfmaUtil
//     stuck at 43% = pure MFMA-floor/serial-sum). Now: builtin s_barrier (no
//     drain) + clobber-free waitcnt asm (template-exact, m201) +
//     sched_barrier(0) fences so ds_reads can't migrate across barriers.
//     Read-ahead reg pipeline + vmcnt ledger unchanged (VMC(8)@ph2,
//     VMC(6)@ph3; tail VMC(4)/VMC(0)).
// ---------------------------------------------------------------------------

#define M_DIM 4096
#define N_DIM 4096
#define K_DIM 4096

typedef __attribute__((ext_vector_type(8))) short bf16x8;   // 8 bf16 = 4 VGPRs
typedef __attribute__((ext_vector_type(4))) float f32x4;    // MFMA C/D

__device__ __forceinline__ unsigned short f32_to_bf16_rne(float f) {
    unsigned u = __float_as_uint(f);
    u += 0x7fffu + ((u >> 16) & 1u);   // round-to-nearest-even
    return (unsigned short)(u >> 16);
}

__device__ __forceinline__ void load_lds16(const void* g, void* l) {
    // async global->LDS, 16 B per lane; LDS dest = wave-uniform base + lane*16
    __builtin_amdgcn_global_load_lds(
        (const __attribute__((address_space(1))) unsigned int*)g,
        (__attribute__((address_space(3))) unsigned int*)l, 16, 0, 0);
}

// ---- fused prologue: blocks [0,16384) dequant W, [16384,32768) convert x ---
__global__ __launch_bounds__(256) void prologue_kernel(
        const int* __restrict__ codes, const float* __restrict__ scales,
        unsigned short* __restrict__ W,
        const float* __restrict__ x, unsigned short* __restrict__ xb) {
    const int bid = blockIdx.x;
    if (bid < 16384) {
        const int tid = bid * 256 + threadIdx.x;      // one thread per int4
        const float s = scales[tid >> 3];             // 8 threads share a scale
        const int4 c  = ((const int4*)codes)[tid];
        union { unsigned short u[4]; uint2 v; } p;
        p.u[0] = f32_to_bf16_rne(s * (float)(c.x - 128));
        p.u[1] = f32_to_bf16_rne(s * (float)(c.y - 128));
        p.u[2] = f32_to_bf16_rne(s * (float)(c.z - 128));
        p.u[3] = f32_to_bf16_rne(s * (float)(c.w - 128));
        ((uint2*)W)[tid] = p.v;
    } else {
        const int tid = (bid - 16384) * 256 + threadIdx.x;  // one per float4
        const float4 f = ((const float4*)x)[tid];
        union { unsigned short u[4]; uint2 v; } p;
        p.u[0] = f32_to_bf16_rne(f.x); p.u[1] = f32_to_bf16_rne(f.y);
        p.u[2] = f32_to_bf16_rne(f.z); p.u[3] = f32_to_bf16_rne(f.w);
        ((uint2*)xb)[tid] = p.v;
    }
}

// ---- sync / pipeline primitives (template-exact: no memory clobbers) ------
#define BAR()   __builtin_amdgcn_s_barrier()
#define VMC(N)  asm volatile("s_waitcnt vmcnt(" #N ")")
#define SB0()   __builtin_amdgcn_sched_barrier(0)

// ---- 8-phase 256x256 bf16 GEMM, both operands K-major, read-ahead regs ----
// LDS: per operand 2 dbuf x 2 khalf regions of [256 rows][32 k] bf16 (16 KB).
// Swizzle: chunk' = chunk ^ ((row>>1)&3); staging pre-swizzles the GLOBAL
//   source k-offset (LDS dest linear); ds_read applies the same XOR.
// Operand groups per K-tile: G0={kh0:a(mh0),b0} G1={kh0:a(mh1)} (b0 reused)
//   G2={kh1:a(mh0),b1} G3={kh1:a(mh1)}. Phase p: read G_{p+1} | stage | BAR |
//   MFMA G_p | BAR. a alternates aX(even G)/aY(odd G); b by k-half.
// In-flight ledger (2 loads per STG): tile-start carry = {Bkh0,Akh0,Bkh1}(T+1)
//   =6. ph0 +Akh1(T+1), ph1 +Bkh0(T+2), ph2 +Akh0(T+2): VMC(8) ensures
//   kh0(T+1) resident for ph3's G0' reads. ph3 +Bkh1(T+2): VMC(6) ensures
//   kh1(T+1) resident for T+1.ph1. Tail: VMC(4)/VMC(0) at tile 62.
__global__ __launch_bounds__(512, 2) void gemm_8phase(
        const unsigned short* __restrict__ A,   // [M,K] bf16 (x)
        const unsigned short* __restrict__ B,   // [N,K] bf16 (W)
        float* __restrict__ C) {                // [M,N] fp32
    __shared__ unsigned short sA[2][2][256 * 32];   // 64 KB
    __shared__ unsigned short sB[2][2][256 * 32];   // 64 KB

    const int tid  = threadIdx.x;
    const int wave = tid >> 6;
    const int lane = tid & 63;

    // XCD rectangle swizzle: xcd = bid%8 owns an 8(m) x 4(n) tile rectangle.
    const int bid  = blockIdx.x;
    const int xcd  = bid & 7;
    const int slot = bid >> 3;                        // 0..31
    const int m0 = ((xcd >> 2) * 8 + (slot >> 2)) * 256;
    const int n0 = ((xcd & 3) * 4 + (slot & 3)) * 256;

    // staging: wave w covers region rows [w*32, w*32+32), 2 calls of 16 rows.
    const int srow   = lane >> 2;
    const int schunk = (lane & 3) ^ ((lane >> 3) & 3);   // pre-swizzled source
    const unsigned short* Ag = A + (size_t)(m0 + wave * 32 + srow) * K_DIM + schunk * 8;
    const unsigned short* Bg = B + (size_t)(n0 + wave * 32 + srow) * K_DIM + schunk * 8;
    const int ldsW = wave * 1024;                        // element offset, call 0

    // fragments: wave (wm,wn) owns C rows [wm*128,+128) x cols [wn*64,+64)
    const int frow = lane & 15;
    const int quad = lane >> 4;
    const int wm = wave >> 2;
    const int wn = wave & 3;
    const int cswz = (quad ^ ((frow >> 1) & 3)) * 8;     // swizzled k-chunk
    const int aOff = (wm * 128 + frow) * 32 + cswz;
    const int bOff = (wn * 64 + frow) * 32 + cswz;

    f32x4 acc[8][4] = {};
    bf16x8 aX[4], aY[4], b0r[4], b1r[4];

#define STG_A(BUF, KH, KT) do { \
        const unsigned short* s_ = Ag + (size_t)(KT) * 64 + (KH) * 32; \
        load_lds16(s_,                       &sA[BUF][KH][ldsW]); \
        load_lds16(s_ + (size_t)16 * K_DIM,  &sA[BUF][KH][ldsW + 512]); \
    } while (0)
#define STG_B(BUF, KH, KT) do { \
        const unsigned short* s_ = Bg + (size_t)(KT) * 64 + (KH) * 32; \
        load_lds16(s_,                       &sB[BUF][KH][ldsW]); \
        load_lds16(s_ + (size_t)16 * K_DIM,  &sB[BUF][KH][ldsW + 512]); \
    } while (0)
#define RD_A4(DST, BUF, KH, MH) do { _Pragma("unroll") \
        for (int i_ = 0; i_ < 4; ++i_) \
            DST[i_] = *(const bf16x8*)&sA[BUF][KH][aOff + ((MH) * 4 + i_) * 512]; \
    } while (0)
#define RD_B4(DST, BUF, KH) do { _Pragma("unroll") \
        for (int i_ = 0; i_ < 4; ++i_) \
            DST[i_] = *(const bf16x8*)&sB[BUF][KH][bOff + i_ * 512]; \
    } while (0)
#define MM16(AR, BR, MH) do { _Pragma("unroll") \
        for (int i_ = 0; i_ < 4; ++i_) { _Pragma("unroll") \
            for (int n_ = 0; n_ < 4; ++n_) \
                acc[(MH) * 4 + i_][n_] = __builtin_amdgcn_mfma_f32_16x16x32_bf16( \
                    AR[i_], BR[n_], acc[(MH) * 4 + i_][n_], 0, 0, 0); \
        } } while (0)

// Phase skeleton: {RD G_{p+1}; STG} SB0 BAR SB0 {setprio MFMA G_p setprio}
//   [VMC] BAR SB0. SB0 pairs pin reads/stages inside their phase (loads are
//   plain LDS ops and could otherwise migrate across the builtin barrier).
#define KTILE(BUF, OBUF, T, I0, I1, I2, I3, VM2, VM3, R3) do { \
        /* ph0: rd G1 | MFMA G0 (aX,b0 -> acc mh0) */ \
        RD_A4(aY, BUF, 0, 1); \
        if (I0) { STG_A(OBUF, 1, (T) + 1); } \
        SB0(); BAR(); SB0(); \
        __builtin_amdgcn_s_setprio(1); MM16(aX, b0r, 0); __builtin_amdgcn_s_setprio(0); \
        BAR(); SB0(); \
        /* ph1: rd G2 | MFMA G1 (aY,b0 -> acc mh1) */ \
        RD_A4(aX, BUF, 1, 0); RD_B4(b1r, BUF, 1); \
        if (I1) { STG_B(BUF, 0, (T) + 2); } \
        SB0(); BAR(); SB0(); \
        __builtin_amdgcn_s_setprio(1); MM16(aY, b0r, 1); __builtin_amdgcn_s_setprio(0); \
        BAR(); SB0(); \
        /* ph2: rd G3 | MFMA G2 (aX,b1 -> acc mh0) */ \
        RD_A4(aY, BUF, 1, 1); \
        if (I2) { STG_A(BUF, 0, (T) + 2); } \
        SB0(); BAR(); SB0(); \
        __builtin_amdgcn_s_setprio(1); MM16(aX, b1r, 0); __builtin_amdgcn_s_setprio(0); \
        VM2; BAR(); SB0(); \
        /* ph3: rd G0' (next tile) | MFMA G3 (aY,b1 -> acc mh1) */ \
        if (R3) { RD_A4(aX, OBUF, 0, 0); RD_B4(b0r, OBUF, 0); } \
        if (I3) { STG_B(BUF, 1, (T) + 2); } \
        SB0(); BAR(); SB0(); \
        __builtin_amdgcn_s_setprio(1); MM16(aY, b1r, 1); __builtin_amdgcn_s_setprio(0); \
        VM3; BAR(); SB0(); \
    } while (0)

    // pipeline prologue: tile 0 all 4 halves + tile 1's {Bkh0,Akh0,Bkh1}
    // (14 loads); vmcnt(6) -> tile 0 resident, 3 halves in flight.
    STG_A(0, 0, 0); STG_B(0, 0, 0); STG_A(0, 1, 0); STG_B(0, 1, 0);
    STG_B(1, 0, 1); STG_A(1, 0, 1); STG_B(1, 1, 1);
    VMC(6); BAR(); SB0();
    // initial register stage: G0 of tile 0
    RD_A4(aX, 0, 0, 0); RD_B4(b0r, 0, 0);

#pragma unroll 1
    for (int t2 = 0; t2 < 31; ++t2) {               // tiles 0..61
        const int t = t2 * 2;
        KTILE(0, 1, t,     1, 1, 1, 1, VMC(8), VMC(6), 1);
        KTILE(1, 0, t + 1, 1, 1, 1, 1, VMC(8), VMC(6), 1);
    }
    KTILE(0, 1, 62, 1, 0, 0, 0, VMC(4), VMC(0), 1); // last issue: Akh1(63)
    KTILE(1, 0, 63, 0, 0, 0, 0, (void)0, (void)0, 0);

    // epilogue: C/D layout col = lane&15, row = quad*4 + r  [m89/m91]
    const size_t crow0 = (size_t)(m0 + wm * 128 + quad * 4);
    const int    ccol  = n0 + wn * 64 + frow;
#pragma unroll
    for (int mt = 0; mt < 8; ++mt)
#pragma unroll
        for (int nt = 0; nt < 4; ++nt)
#pragma unroll
            for (int r = 0; r < 4; ++r)
                C[(crow0 + mt * 16 + r) * N_DIM + ccol + nt * 16] = acc[mt][nt][r];

#undef STG_A
#undef STG_B
#undef RD_A4
#undef RD_B4
#undef MM16
#undef KTILE
}

extern "C" void kernel_launch(void* const* d_in, const int* in_sizes, int n_in,
                              void* d_out, int out_size, void* d_ws, size_t ws_size,
                              hipStream_t stream) {
    const float* x      = (const float*)d_in[0];   // 2*2048*4096 fp32
    const float* scales = (const float*)d_in[1];   // 4096*128 fp32
    const int*   codes  = (const int*)d_in[2];     // 4096*128*32 int32
    float* y = (float*)d_out;                      // 4096*4096 fp32

    unsigned short* Wb = (unsigned short*)d_ws;                       // 32 MB
    unsigned short* xb = (unsigned short*)((char*)d_ws + (size_t)N_DIM * K_DIM * 2); // 32 MB

    prologue_kernel<<<32768, 256, 0, stream>>>(codes, scales, Wb, x, xb);

    gemm_8phase<<<256, 512, 0, stream>>>(xb, Wb, y);
}